// Round 3
// baseline (5576.590 us; speedup 1.0000x reference)
//
#include <hip/hip_runtime.h>

#define KN  50
#define NM  10          // MBON == DAN == 10
#define LPB 16          // lanes per batch element

typedef float v2f __attribute__((ext_vector_type(2)));

// mov_dpp(old=0,bound_ctrl=1) + fadd; GCNDPPCombine fuses into v_add_f32_dpp (1 inst)
template <int CTRL>
__device__ __forceinline__ float dpp_add(float x) {
  return x + __int_as_float(
      __builtin_amdgcn_update_dpp(0, __float_as_int(x), CTRL, 0xF, 0xF, true));
}

__device__ __forceinline__ float rowsum16(float x) {
  x = dpp_add<0x121>(x);   // row_ror:1
  x = dpp_add<0x122>(x);   // row_ror:2
  x = dpp_add<0x124>(x);   // row_ror:4
  x = dpp_add<0x128>(x);   // row_ror:8
  return x;
}

extern "C" __global__ void __launch_bounds__(256)
// (4,4): min=max=4 waves/SIMD -> hard 128-VGPR budget. Current footprint is 104 regs,
// so the persistent plastic state still fits WITHOUT spill, and occupancy doubles vs
// the old (2,2) pin (22% -> ~44%) to hide LDS/DPP latency.
// Round-1 lesson: min-only waves_per_eu(4) (unbounded max) let the heuristic crush to
// 64 regs and spill the state -> 10 GB/dispatch HBM. min=max is the safe form.
// Canary: FETCH_SIZE >> 123 MB means spill -> fall back to (3,3).
__attribute__((amdgpu_waves_per_eu(4, 4)))
fly_kernel(const float* __restrict__ odor,    // [T,B,3]
           const float* __restrict__ ctxp,    // [T,B,1]
           const float* __restrict__ pn_w,    // [B,3,KN]
           const float* __restrict__ kn_b,    // [KN]
           const float* __restrict__ apl_w,   // [KN,1]
           const float* __restrict__ apl_b,   // [1]
           const float* __restrict__ mdw_g,   // mbon_dan_weight [DAN,MBON]
           const float* __restrict__ mbon_b,  // [MBON]
           const float* __restrict__ dmw_g,   // dan_mbon_weight [MBON,DAN]
           const float* __restrict__ ddw_g,   // dan_dan_weight [DAN,DAN]
           const float* __restrict__ dcw_g,   // dan_context_weight [1,DAN]
           const float* __restrict__ dan_b,   // [DAN]
           const float* __restrict__ decW,    // [2,MBON]
           const float* __restrict__ decb,    // [2]
           const float* __restrict__ kcw0,    // [B,KN,MBON]
           const float* __restrict__ wact0,   // [B,KN,MBON]
           float* __restrict__ out,           // [T,B,2]
           int B, int T)
{
  // per-group broadcast buffers; each 16-lane group is within one wave -> DS pipe
  // in-order, no barriers. stride 16 floats: 2-way bank alias across groups = free.
  __shared__ float smb[16][16];   // mbon broadcast
  __shared__ float sdn[16][16];   // dan broadcast

  const int tid   = threadIdx.x;
  const int j     = tid & (LPB - 1);
  const int jhalf = j >> 1;
  const int jodd  = j & 1;
  const int g     = tid >> 4;                 // group within block
  const int b     = blockIdx.x * (256 / LPB) + g;
  if (b >= B) return;

  const bool has4 = (j + 48) < KN;            // lanes 0,1 own a 4th k-row

  // ---- persistent plastic state + per-batch weights (VGPRs) ----
  // wct holds Bq = 0.25*wact (exact pow2 scale) so kc_w update is a single pk_fma.
  v2f   kcw[4][5], wct[4][5];                 // rows j,16+j,32+j,48+j  x  10 cols (packed)
  float pw0[4], pw1[4], pw2[4], knb[4], aw[4];
  float kcn[4] = {0.f,0.f,0.f,0.f}, lkc[4] = {0.f,0.f,0.f,0.f};

  #pragma unroll
  for (int i = 0; i < 4; ++i) {
    const int k = j + 16 * i;
    if (i < 3 || has4) {
      const v2f* a = reinterpret_cast<const v2f*>(kcw0  + ((size_t)b * KN + k) * NM);
      const v2f* w = reinterpret_cast<const v2f*>(wact0 + ((size_t)b * KN + k) * NM);
      #pragma unroll
      for (int h = 0; h < 5; ++h) { kcw[i][h] = a[h]; wct[i][h] = 0.25f * w[h]; }
      pw0[i] = pn_w[((size_t)b * 3 + 0) * KN + k];
      pw1[i] = pn_w[((size_t)b * 3 + 1) * KN + k];
      pw2[i] = pn_w[((size_t)b * 3 + 2) * KN + k];
      knb[i] = kn_b[k];
      aw[i]  = apl_w[k];
    } else {
      #pragma unroll
      for (int h = 0; h < 5; ++h) { kcw[i][h] = (v2f)(0.f); wct[i][h] = (v2f)(0.f); }
      pw0[i] = pw1[i] = pw2[i] = 0.f; knb[i] = 0.f; aw[i] = 0.f;
    }
  }

  // ---- per-column (m == j) small weights, packed; lanes j>=10 hold zeros ----
  v2f   mdw2[5], ddw2[5], dmw2[5];
  float cw = 0.f, db_ = 0.f, mb_ = 0.f, dw0 = 0.f, dw1 = 0.f;
  #pragma unroll
  for (int h = 0; h < 5; ++h) { mdw2[h] = (v2f)(0.f); ddw2[h] = (v2f)(0.f); dmw2[h] = (v2f)(0.f); }
  if (j < NM) {
    #pragma unroll
    for (int h = 0; h < 5; ++h) {
      mdw2[h].x = mdw_g[(2*h)   * NM + j];  mdw2[h].y = mdw_g[(2*h+1) * NM + j];
      ddw2[h].x = ddw_g[(2*h)   * NM + j];  ddw2[h].y = ddw_g[(2*h+1) * NM + j];
      dmw2[h].x = dmw_g[(2*h)   * NM + j];  dmw2[h].y = dmw_g[(2*h+1) * NM + j];
    }
    cw  = dcw_g[j];
    db_ = dan_b[j];
    mb_ = mbon_b[j];
    dw0 = decW[j];
    dw1 = decW[NM + j];
  }
  const float aplb = apl_b[0];
  const float db0 = decb[0], db1 = decb[1];

  const float ALPHA = (float)(0.5 / 5.5);     // DT/(DT+RC)

  // ---- recurrent small state ----
  float apl = 0.f, mbon_m = 0.f, dan_m = 0.f;
  v2f dvec2[5], ldv2[5];
  #pragma unroll
  for (int h = 0; h < 5; ++h) { dvec2[h] = (v2f)(0.f); ldv2[h] = (v2f)(0.f); }

  // input pointers (strength-reduced); prefetch t=0
  const float* op = odor + (size_t)b * 3;
  const float* cp = ctxp + b;
  const size_t so = (size_t)B * 3;
  float o0n = op[0], o1n = op[1], o2n = op[2];
  float cxn = *cp;

  for (int t = 0; t < T; ++t) {
    const float o0 = o0n, o1 = o1n, o2 = o2n, cx = cxn;
    if (t + 1 < T) {                       // prefetch next step's inputs
      op += so; cp += B;
      o0n = op[0]; o1n = op[1]; o2n = op[2]; cxn = *cp;
    }

    // --- Kenyon update (own k-rows) + packed kc_value/apl partial sums ---
    float psum = 0.f;
    v2f p2[5];
    #pragma unroll
    for (int h = 0; h < 5; ++h) p2[h] = (v2f)(0.f);

    #pragma unroll
    for (int i = 0; i < 4; ++i) {
      if (i < 3 || has4) {
        const float base = knb[i] - apl;                 // fold bias-apl into fma chain
        float pv = fmaf(pw0[i], o0, fmaf(pw1[i], o1, fmaf(pw2[i], o2, base)));
        float r  = fmaxf(pv, 0.f);
        float kn = 0.5f * (kcn[i] + r);                  // dt_tau = 0.5
        kcn[i] = kn;
        lkc[i] = fmaf(ALPHA, kn - lkc[i], lkc[i]);       // low_kc_n (new kc_n)
        psum = fmaf(kn, aw[i], psum);
        #pragma unroll
        for (int h = 0; h < 5; ++h) p2[h] += kn * kcw[i][h];  // vs pre-update kc_w
      }
    }

    psum = rowsum16(psum);
    #pragma unroll
    for (int h = 0; h < 5; ++h) {
      p2[h].x = rowsum16(p2[h].x);
      p2[h].y = rowsum16(p2[h].y);
    }

    apl = 0.5f * apl + 0.5f * fmaxf(psum + aplb, 0.f);

    // select this lane's column value
    v2f rsel = p2[0];
    #pragma unroll
    for (int h = 1; h < 5; ++h) rsel = (jhalf == h) ? p2[h] : rsel;
    const float kcv = jodd ? rsel.y : rsel.x;

    // --- MBON (column j): dan_mod uses PREVIOUS dan ---
    v2f s2 = dvec2[0] * mdw2[0];
    #pragma unroll
    for (int e = 1; e < 5; ++e) s2 += dvec2[e] * mdw2[e];
    const float s = s2.x + s2.y;
    const float dmod = 1.f / (1.f + __expf(-s));
    mbon_m = 0.5f * mbon_m + 0.5f * dmod * fmaxf(kcv + mb_, 0.f);
    smb[g][j] = mbon_m;                         // broadcast via LDS (same wave, in-order)

    // --- DAN (column j): previous dan + new mbon (packed LDS gather) ---
    v2f acc = dvec2[0] * ddw2[0];
    #pragma unroll
    for (int e = 1; e < 5; ++e) acc += dvec2[e] * ddw2[e];
    {
      const v2f* pm = reinterpret_cast<const v2f*>(&smb[g][0]);
      #pragma unroll
      for (int h = 0; h < 5; ++h) acc += pm[h] * dmw2[h];
    }
    float dp = acc.x + acc.y + fmaf(cx, cw, db_);
    dan_m = 0.5f * dan_m + 0.5f * fmaxf(dp, 0.f);
    sdn[g][j] = dan_m;

    // --- fill the sdn write->read latency shadow with independent work ---
    // decoder output: depends only on mbon_m
    const float q0 = rowsum16(mbon_m * dw0) + db0;
    const float q1 = rowsum16(mbon_m * dw1) + db1;
    if (j == 0) {
      float2 st; st.x = q0; st.y = q1;
      *reinterpret_cast<float2*>(out + ((size_t)t * B + b) * 2) = st;
    }
    // kc_w decay: kc_w' = 0.75*kc_w + Bq  (uses Bq BEFORE syn; independent of new dan)
    #pragma unroll
    for (int i = 0; i < 4; ++i) {
      if (i < 3 || has4) {
        #pragma unroll
        for (int h = 0; h < 5; ++h) kcw[i][h] = 0.75f * kcw[i][h] + wct[i][h];
      }
    }

    // re-read all 10 dan values packed; update low_dan
    {
      const v2f* pd = reinterpret_cast<const v2f*>(&sdn[g][0]);
      #pragma unroll
      for (int e = 0; e < 5; ++e) {
        dvec2[e] = pd[e];
        ldv2[e] += ALPHA * (dvec2[e] - ldv2[e]);          // low_dan_n (new dan)
      }
    }

    // --- plasticity trace: Bq' = Bq + 0.125*(kcn*ldv - lkc*dv)  (needs NEW dan/low_dan)
    #pragma unroll
    for (int i = 0; i < 4; ++i) {
      if (i < 3 || has4) {
        const float kh  =  0.125f * kcn[i];    // 0.25 * DT * kc_n
        const float nlh = -0.125f * lkc[i];    // -0.25 * DT * low_kc_n
        #pragma unroll
        for (int h = 0; h < 5; ++h)
          wct[i][h] = wct[i][h] + kh * ldv2[h] + nlh * dvec2[h];   // Bq_n
      }
    }
  }
}

extern "C" void kernel_launch(void* const* d_in, const int* in_sizes, int n_in,
                              void* d_out, int out_size, void* d_ws, size_t ws_size,
                              hipStream_t stream) {
  const float* odor   = (const float*)d_in[0];
  const float* ctx    = (const float*)d_in[1];
  const float* pn_w   = (const float*)d_in[2];
  const float* kn_b   = (const float*)d_in[3];
  const float* apl_w  = (const float*)d_in[4];
  const float* apl_b  = (const float*)d_in[5];
  const float* mdw    = (const float*)d_in[6];
  const float* mbon_b = (const float*)d_in[7];
  const float* dmw    = (const float*)d_in[8];
  const float* ddw    = (const float*)d_in[9];
  const float* dcw    = (const float*)d_in[10];
  const float* dan_b  = (const float*)d_in[11];
  const float* decW   = (const float*)d_in[12];
  const float* decb   = (const float*)d_in[13];
  const float* kcw0   = (const float*)d_in[14];
  const float* wact0  = (const float*)d_in[15];
  float* out = (float*)d_out;

  const int B = in_sizes[14] / (KN * NM);   // kc_weight0 is [B,50,10]
  const int T = in_sizes[0] / (B * 3);      // odor is [T,B,3]

  const int batches_per_block = 256 / LPB;  // 16
  dim3 grid((B + batches_per_block - 1) / batches_per_block);
  dim3 block(256);
  hipLaunchKernelGGL(fly_kernel, grid, block, 0, stream,
                     odor, ctx, pn_w, kn_b, apl_w, apl_b,
                     mdw, mbon_b, dmw, ddw, dcw, dan_b,
                     decW, decb, kcw0, wact0, out, B, T);
}

// Round 4
// 822.394 us; speedup vs baseline: 6.7809x; 6.7809x over previous
//
#include <hip/hip_runtime.h>

#define KN  50
#define NM  10          // MBON == DAN == 10
#define LPB 16          // lanes per batch element

typedef float v2f __attribute__((ext_vector_type(2)));

// mov_dpp(old=0,bound_ctrl=1) + fadd; GCNDPPCombine fuses into v_add_f32_dpp (1 inst)
template <int CTRL>
__device__ __forceinline__ float dpp_add(float x) {
  return x + __int_as_float(
      __builtin_amdgcn_update_dpp(0, __float_as_int(x), CTRL, 0xF, 0xF, true));
}

__device__ __forceinline__ float rowsum16(float x) {
  x = dpp_add<0x121>(x);   // row_ror:1
  x = dpp_add<0x122>(x);   // row_ror:2
  x = dpp_add<0x124>(x);   // row_ror:4
  x = dpp_add<0x128>(x);   // row_ror:8
  return x;
}

__device__ __forceinline__ float bcast(int idx4, float x) {
  return __int_as_float(__builtin_amdgcn_ds_bpermute(idx4, __float_as_int(x)));
}

// ============================================================================
// Variant A: low-inst-count LDS-broadcast body, 3 waves/SIMD (~168-VGPR budget).
// Occupancy theory: round-0 is stall-dominated (true issue occupancy ~41%), a
// 3rd wave/SIMD should cut ~30%. Risk: spill cascade (seen at 128-reg budget).
// kernel_launch checks localSizeBytes and falls back to Variant B if spilled.
// ============================================================================
__global__ void __launch_bounds__(256)
__attribute__((amdgpu_waves_per_eu(3, 3)))
fly_w3(const float* __restrict__ odor,    // [T,B,3]
       const float* __restrict__ ctxp,    // [T,B,1]
       const float* __restrict__ pn_w,    // [B,3,KN]
       const float* __restrict__ kn_b,    // [KN]
       const float* __restrict__ apl_w,   // [KN,1]
       const float* __restrict__ apl_b,   // [1]
       const float* __restrict__ mdw_g,   // mbon_dan_weight [DAN,MBON]
       const float* __restrict__ mbon_b,  // [MBON]
       const float* __restrict__ dmw_g,   // dan_mbon_weight [MBON,DAN]
       const float* __restrict__ ddw_g,   // dan_dan_weight [DAN,DAN]
       const float* __restrict__ dcw_g,   // dan_context_weight [1,DAN]
       const float* __restrict__ dan_b,   // [DAN]
       const float* __restrict__ decW,    // [2,MBON]
       const float* __restrict__ decb,    // [2]
       const float* __restrict__ kcw0,    // [B,KN,MBON]
       const float* __restrict__ wact0,   // [B,KN,MBON]
       float* __restrict__ out,           // [T,B,2]
       int B, int T)
{
  __shared__ float smb[16][16];   // mbon broadcast
  __shared__ float sdn[16][16];   // dan broadcast

  const int tid   = threadIdx.x;
  const int j     = tid & (LPB - 1);
  const int jhalf = j >> 1;
  const int jodd  = j & 1;
  const int g     = tid >> 4;
  const int b     = blockIdx.x * (256 / LPB) + g;
  if (b >= B) return;

  const bool has4 = (j + 48) < KN;

  v2f   kcw[4][5], wct[4][5];               // wct holds Bq = 0.25*wact (pow2-exact)
  float pw0[4], pw1[4], pw2[4], knb[4], aw[4];
  float kcn[4] = {0.f,0.f,0.f,0.f}, lkc[4] = {0.f,0.f,0.f,0.f};

  #pragma unroll
  for (int i = 0; i < 4; ++i) {
    const int k = j + 16 * i;
    if (i < 3 || has4) {
      const v2f* a = reinterpret_cast<const v2f*>(kcw0  + ((size_t)b * KN + k) * NM);
      const v2f* w = reinterpret_cast<const v2f*>(wact0 + ((size_t)b * KN + k) * NM);
      #pragma unroll
      for (int h = 0; h < 5; ++h) { kcw[i][h] = a[h]; wct[i][h] = 0.25f * w[h]; }
      pw0[i] = pn_w[((size_t)b * 3 + 0) * KN + k];
      pw1[i] = pn_w[((size_t)b * 3 + 1) * KN + k];
      pw2[i] = pn_w[((size_t)b * 3 + 2) * KN + k];
      knb[i] = kn_b[k];
      aw[i]  = apl_w[k];
    } else {
      #pragma unroll
      for (int h = 0; h < 5; ++h) { kcw[i][h] = (v2f)(0.f); wct[i][h] = (v2f)(0.f); }
      pw0[i] = pw1[i] = pw2[i] = 0.f; knb[i] = 0.f; aw[i] = 0.f;
    }
  }

  v2f   mdw2[5], ddw2[5], dmw2[5];
  float cw = 0.f, db_ = 0.f, mb_ = 0.f, dw0 = 0.f, dw1 = 0.f;
  #pragma unroll
  for (int h = 0; h < 5; ++h) { mdw2[h] = (v2f)(0.f); ddw2[h] = (v2f)(0.f); dmw2[h] = (v2f)(0.f); }
  if (j < NM) {
    #pragma unroll
    for (int h = 0; h < 5; ++h) {
      mdw2[h].x = mdw_g[(2*h)   * NM + j];  mdw2[h].y = mdw_g[(2*h+1) * NM + j];
      ddw2[h].x = ddw_g[(2*h)   * NM + j];  ddw2[h].y = ddw_g[(2*h+1) * NM + j];
      dmw2[h].x = dmw_g[(2*h)   * NM + j];  dmw2[h].y = dmw_g[(2*h+1) * NM + j];
    }
    cw  = dcw_g[j];
    db_ = dan_b[j];
    mb_ = mbon_b[j];
    dw0 = decW[j];
    dw1 = decW[NM + j];
  }
  const float aplb = apl_b[0];
  const float db0 = decb[0], db1 = decb[1];

  const float ALPHA = (float)(0.5 / 5.5);

  float apl = 0.f, mbon_m = 0.f, dan_m = 0.f;
  v2f dvec2[5], ldv2[5];
  #pragma unroll
  for (int h = 0; h < 5; ++h) { dvec2[h] = (v2f)(0.f); ldv2[h] = (v2f)(0.f); }

  const float* op = odor + (size_t)b * 3;
  const float* cp = ctxp + b;
  const size_t so = (size_t)B * 3;
  float o0n = op[0], o1n = op[1], o2n = op[2];
  float cxn = *cp;

  for (int t = 0; t < T; ++t) {
    const float o0 = o0n, o1 = o1n, o2 = o2n, cx = cxn;
    if (t + 1 < T) {
      op += so; cp += B;
      o0n = op[0]; o1n = op[1]; o2n = op[2]; cxn = *cp;
    }

    float psum = 0.f;
    v2f p2[5];
    #pragma unroll
    for (int h = 0; h < 5; ++h) p2[h] = (v2f)(0.f);

    #pragma unroll
    for (int i = 0; i < 4; ++i) {
      if (i < 3 || has4) {
        const float base = knb[i] - apl;
        float pv = fmaf(pw0[i], o0, fmaf(pw1[i], o1, fmaf(pw2[i], o2, base)));
        float r  = fmaxf(pv, 0.f);
        float kn = 0.5f * (kcn[i] + r);
        kcn[i] = kn;
        lkc[i] = fmaf(ALPHA, kn - lkc[i], lkc[i]);
        psum = fmaf(kn, aw[i], psum);
        #pragma unroll
        for (int h = 0; h < 5; ++h) p2[h] += kn * kcw[i][h];
      }
    }

    psum = rowsum16(psum);
    #pragma unroll
    for (int h = 0; h < 5; ++h) {
      p2[h].x = rowsum16(p2[h].x);
      p2[h].y = rowsum16(p2[h].y);
    }

    apl = 0.5f * apl + 0.5f * fmaxf(psum + aplb, 0.f);

    v2f rsel = p2[0];
    #pragma unroll
    for (int h = 1; h < 5; ++h) rsel = (jhalf == h) ? p2[h] : rsel;
    const float kcv = jodd ? rsel.y : rsel.x;

    v2f s2 = dvec2[0] * mdw2[0];
    #pragma unroll
    for (int e = 1; e < 5; ++e) s2 += dvec2[e] * mdw2[e];
    const float s = s2.x + s2.y;
    const float dmod = 1.f / (1.f + __expf(-s));
    mbon_m = 0.5f * mbon_m + 0.5f * dmod * fmaxf(kcv + mb_, 0.f);
    smb[g][j] = mbon_m;

    v2f acc = dvec2[0] * ddw2[0];
    #pragma unroll
    for (int e = 1; e < 5; ++e) acc += dvec2[e] * ddw2[e];
    {
      const v2f* pm = reinterpret_cast<const v2f*>(&smb[g][0]);
      #pragma unroll
      for (int h = 0; h < 5; ++h) acc += pm[h] * dmw2[h];
    }
    float dp = acc.x + acc.y + fmaf(cx, cw, db_);
    dan_m = 0.5f * dan_m + 0.5f * fmaxf(dp, 0.f);
    sdn[g][j] = dan_m;

    // fill the sdn write->read shadow with independent work
    const float q0 = rowsum16(mbon_m * dw0) + db0;
    const float q1 = rowsum16(mbon_m * dw1) + db1;
    if (j == 0) {
      float2 st; st.x = q0; st.y = q1;
      *reinterpret_cast<float2*>(out + ((size_t)t * B + b) * 2) = st;
    }
    #pragma unroll
    for (int i = 0; i < 4; ++i) {
      if (i < 3 || has4) {
        #pragma unroll
        for (int h = 0; h < 5; ++h) kcw[i][h] = 0.75f * kcw[i][h] + wct[i][h];
      }
    }

    {
      const v2f* pd = reinterpret_cast<const v2f*>(&sdn[g][0]);
      #pragma unroll
      for (int e = 0; e < 5; ++e) {
        dvec2[e] = pd[e];
        ldv2[e] += ALPHA * (dvec2[e] - ldv2[e]);
      }
    }

    #pragma unroll
    for (int i = 0; i < 4; ++i) {
      if (i < 3 || has4) {
        const float kh  =  0.125f * kcn[i];
        const float nlh = -0.125f * lkc[i];
        #pragma unroll
        for (int h = 0; h < 5; ++h)
          wct[i][h] = wct[i][h] + kh * ldv2[h] + nlh * dvec2[h];
      }
    }
  }
}

// ============================================================================
// Variant B: round-0 kernel VERBATIM (proven 765 us dispatch). Fallback when
// Variant A spills (localSizeBytes != 0).
// ============================================================================
__global__ void __launch_bounds__(256)
__attribute__((amdgpu_waves_per_eu(2, 2)))
fly_w2(const float* __restrict__ odor,
       const float* __restrict__ ctxp,
       const float* __restrict__ pn_w,
       const float* __restrict__ kn_b,
       const float* __restrict__ apl_w,
       const float* __restrict__ apl_b,
       const float* __restrict__ mdw_g,
       const float* __restrict__ mbon_b,
       const float* __restrict__ dmw_g,
       const float* __restrict__ ddw_g,
       const float* __restrict__ dcw_g,
       const float* __restrict__ dan_b,
       const float* __restrict__ decW,
       const float* __restrict__ decb,
       const float* __restrict__ kcw0,
       const float* __restrict__ wact0,
       float* __restrict__ out,
       int B, int T)
{
  const int tid   = threadIdx.x;
  const int j     = tid & (LPB - 1);
  const int jhalf = j >> 1;
  const int jodd  = j & 1;
  const int b     = blockIdx.x * (256 / LPB) + (tid >> 4);
  if (b >= B) return;

  const int base4 = (tid & 48) << 2;          // byte index of lane 0 of this 16-lane group
  const bool has4 = (j + 48) < KN;

  v2f   kcw[4][5], wct[4][5];
  float pw0[4], pw1[4], pw2[4], knb[4], aw[4];
  float kcn[4] = {0.f,0.f,0.f,0.f}, lkc[4] = {0.f,0.f,0.f,0.f};

  #pragma unroll
  for (int i = 0; i < 4; ++i) {
    const int k = j + 16 * i;
    if (i < 3 || has4) {
      const v2f* a = reinterpret_cast<const v2f*>(kcw0  + ((size_t)b * KN + k) * NM);
      const v2f* w = reinterpret_cast<const v2f*>(wact0 + ((size_t)b * KN + k) * NM);
      #pragma unroll
      for (int h = 0; h < 5; ++h) { kcw[i][h] = a[h]; wct[i][h] = w[h]; }
      pw0[i] = pn_w[((size_t)b * 3 + 0) * KN + k];
      pw1[i] = pn_w[((size_t)b * 3 + 1) * KN + k];
      pw2[i] = pn_w[((size_t)b * 3 + 2) * KN + k];
      knb[i] = kn_b[k];
      aw[i]  = apl_w[k];
    } else {
      #pragma unroll
      for (int h = 0; h < 5; ++h) { kcw[i][h] = (v2f)(0.f); wct[i][h] = (v2f)(0.f); }
      pw0[i] = pw1[i] = pw2[i] = 0.f; knb[i] = 0.f; aw[i] = 0.f;
    }
  }

  v2f   mdw2[5], ddw2[5];
  float dmw[NM];
  float cw = 0.f, db_ = 0.f, mb_ = 0.f, dw0 = 0.f, dw1 = 0.f;
  #pragma unroll
  for (int h = 0; h < 5; ++h) { mdw2[h] = (v2f)(0.f); ddw2[h] = (v2f)(0.f); }
  #pragma unroll
  for (int m = 0; m < NM; ++m) dmw[m] = 0.f;
  if (j < NM) {
    #pragma unroll
    for (int h = 0; h < 5; ++h) {
      mdw2[h].x = mdw_g[(2*h)   * NM + j];  mdw2[h].y = mdw_g[(2*h+1) * NM + j];
      ddw2[h].x = ddw_g[(2*h)   * NM + j];  ddw2[h].y = ddw_g[(2*h+1) * NM + j];
    }
    #pragma unroll
    for (int m = 0; m < NM; ++m) dmw[m] = dmw_g[m * NM + j];
    cw  = dcw_g[j];
    db_ = dan_b[j];
    mb_ = mbon_b[j];
    dw0 = decW[j];
    dw1 = decW[NM + j];
  }
  const float aplb = apl_b[0];
  const float db0 = decb[0], db1 = decb[1];

  const float ALPHA = (float)(0.5 / 5.5);

  float apl = 0.f, mbon_m = 0.f, dan_m = 0.f;
  v2f dvec2[5], ldv2[5];
  #pragma unroll
  for (int h = 0; h < 5; ++h) { dvec2[h] = (v2f)(0.f); ldv2[h] = (v2f)(0.f); }

  size_t ob = (size_t)b * 3;
  float o0n = odor[ob], o1n = odor[ob + 1], o2n = odor[ob + 2];
  float cxn = ctxp[b];

  for (int t = 0; t < T; ++t) {
    const float o0 = o0n, o1 = o1n, o2 = o2n, cx = cxn;
    {
      const int tn = (t + 1 < T) ? t + 1 : t;
      const size_t obn = ((size_t)tn * B + b) * 3;
      o0n = odor[obn]; o1n = odor[obn + 1]; o2n = odor[obn + 2];
      cxn = ctxp[(size_t)tn * B + b];
    }

    float psum = 0.f;
    v2f p2[5];
    #pragma unroll
    for (int h = 0; h < 5; ++h) p2[h] = (v2f)(0.f);

    #pragma unroll
    for (int i = 0; i < 4; ++i) {
      if (i < 3 || has4) {
        float pv = fmaf(pw0[i], o0, fmaf(pw1[i], o1, pw2[i] * o2));
        float r  = fmaxf(pv - apl + knb[i], 0.f);
        float kn = 0.5f * (kcn[i] + r);
        kcn[i] = kn;
        lkc[i] = fmaf(ALPHA, kn - lkc[i], lkc[i]);
        psum = fmaf(kn, aw[i], psum);
        #pragma unroll
        for (int h = 0; h < 5; ++h) p2[h] += kn * kcw[i][h];
      }
    }

    psum = rowsum16(psum);
    #pragma unroll
    for (int h = 0; h < 5; ++h) {
      p2[h].x = rowsum16(p2[h].x);
      p2[h].y = rowsum16(p2[h].y);
    }

    apl = 0.5f * apl + 0.5f * fmaxf(psum + aplb, 0.f);

    v2f rsel = p2[0];
    #pragma unroll
    for (int h = 1; h < 5; ++h) rsel = (jhalf == h) ? p2[h] : rsel;
    const float kcv = jodd ? rsel.y : rsel.x;

    v2f s2 = dvec2[0] * mdw2[0];
    #pragma unroll
    for (int e = 1; e < 5; ++e) s2 += dvec2[e] * mdw2[e];
    const float s = s2.x + s2.y;
    const float dmod = 1.f / (1.f + __expf(-s));
    mbon_m = 0.5f * mbon_m + 0.5f * dmod * fmaxf(kcv + mb_, 0.f);

    v2f dp2 = dvec2[0] * ddw2[0];
    #pragma unroll
    for (int e = 1; e < 5; ++e) dp2 += dvec2[e] * ddw2[e];
    float dp = dp2.x + dp2.y + fmaf(cx, cw, db_);
    #pragma unroll
    for (int m = 0; m < NM; ++m)
      dp = fmaf(bcast(base4 + 4 * m, mbon_m), dmw[m], dp);
    dan_m = 0.5f * dan_m + 0.5f * fmaxf(dp, 0.f);

    #pragma unroll
    for (int e = 0; e < 5; ++e) {
      dvec2[e].x = bcast(base4 + 8 * e,     dan_m);
      dvec2[e].y = bcast(base4 + 8 * e + 4, dan_m);
      ldv2[e] += ALPHA * (dvec2[e] - ldv2[e]);
    }

    const float q0 = rowsum16(mbon_m * dw0) + db0;
    const float q1 = rowsum16(mbon_m * dw1) + db1;
    if (j == 0) {
      float2 st; st.x = q0; st.y = q1;
      *reinterpret_cast<float2*>(out + ((size_t)t * B + b) * 2) = st;
    }

    #pragma unroll
    for (int i = 0; i < 4; ++i) {
      if (i < 3 || has4) {
        const float kh  =  0.5f * kcn[i];
        const float nlh = -0.5f * lkc[i];
        #pragma unroll
        for (int h = 0; h < 5; ++h) {
          const v2f w = wct[i][h];
          kcw[i][h] = 0.75f * kcw[i][h] + 0.25f * w;
          wct[i][h] = w + kh * ldv2[h] + nlh * dvec2[h];
        }
      }
    }
  }
}

extern "C" void kernel_launch(void* const* d_in, const int* in_sizes, int n_in,
                              void* d_out, int out_size, void* d_ws, size_t ws_size,
                              hipStream_t stream) {
  const float* odor   = (const float*)d_in[0];
  const float* ctx    = (const float*)d_in[1];
  const float* pn_w   = (const float*)d_in[2];
  const float* kn_b   = (const float*)d_in[3];
  const float* apl_w  = (const float*)d_in[4];
  const float* apl_b  = (const float*)d_in[5];
  const float* mdw    = (const float*)d_in[6];
  const float* mbon_b = (const float*)d_in[7];
  const float* dmw    = (const float*)d_in[8];
  const float* ddw    = (const float*)d_in[9];
  const float* dcw    = (const float*)d_in[10];
  const float* dan_b  = (const float*)d_in[11];
  const float* decW   = (const float*)d_in[12];
  const float* decb   = (const float*)d_in[13];
  const float* kcw0   = (const float*)d_in[14];
  const float* wact0  = (const float*)d_in[15];
  float* out = (float*)d_out;

  const int B = in_sizes[14] / (KN * NM);   // kc_weight0 is [B,50,10]
  const int T = in_sizes[0] / (B * 3);      // odor is [T,B,3]

  const int batches_per_block = 256 / LPB;  // 16
  dim3 grid((B + batches_per_block - 1) / batches_per_block);
  dim3 block(256);

  // Host-side spill check on the 3-wave variant (cached; graph-capture-safe:
  // pure host query, no stream/alloc/sync operations).
  static int use_w3 = -1;
  if (use_w3 < 0) {
    hipFuncAttributes attr{};
    hipError_t err = hipFuncGetAttributes(&attr, reinterpret_cast<const void*>(fly_w3));
    use_w3 = (err == hipSuccess && attr.localSizeBytes == 0) ? 1 : 0;
  }

  if (use_w3) {
    hipLaunchKernelGGL(fly_w3, grid, block, 0, stream,
                       odor, ctx, pn_w, kn_b, apl_w, apl_b,
                       mdw, mbon_b, dmw, ddw, dcw, dan_b,
                       decW, decb, kcw0, wact0, out, B, T);
  } else {
    hipLaunchKernelGGL(fly_w2, grid, block, 0, stream,
                       odor, ctx, pn_w, kn_b, apl_w, apl_b,
                       mdw, mbon_b, dmw, ddw, dcw, dan_b,
                       decW, decb, kcw0, wact0, out, B, T);
  }
}